// Round 2
// baseline (701.123 us; speedup 1.0000x reference)
//
#include <hip/hip_runtime.h>

#define DIM   64
#define G3    192      // 3*DIM
#define NB    512      // BATCH
#define NM    32       // N_MEM
#define NRELS 32
#define KGE_W 0.01f
#define L2_W  1e-7f
#define EPSC  1e-7f

// ---------- helpers ----------

__device__ inline float bcast(float v, int srclane) {
    // wave-uniform lane broadcast via readlane (index is wave-uniform at all call sites)
    return __int_as_float(__builtin_amdgcn_readlane(__float_as_int(v), srclane));
}

__device__ inline float sigmoidf_(float x) { return 1.0f / (1.0f + __expf(-x)); }
__device__ inline float tanhf_(float x)    { return 1.0f - 2.0f / (1.0f + __expf(2.0f * x)); }

__device__ inline float wave_sum(float v) {
#pragma unroll
    for (int off = 32; off > 0; off >>= 1) v += __shfl_xor(v, off, 64);
    return v;
}
__device__ inline float wave_max(float v) {
#pragma unroll
    for (int off = 32; off > 0; off >>= 1) v = fmaxf(v, __shfl_xor(v, off, 64));
    return v;
}

// LDS-only barrier: does NOT drain vmcnt (global prefetch loads / ys stores
// stay in flight across it, unlike __syncthreads()).
__device__ __forceinline__ void barrier_lds() {
    asm volatile("s_waitcnt lgkmcnt(0)" ::: "memory");
    __builtin_amdgcn_s_barrier();
    asm volatile("" ::: "memory");
}

// ---------- GRU scan (single block, 256 threads = 4 waves) ----------
// Per step t: gh = whh @ h + bhh (k-sliced across 4 waves, partials reduced in
// LDS), gates computed redundantly in every wave so h stays replicated in lane
// registers. One LDS-only barrier per step (double-buffered partial slots).
// GI is software-pipelined 2 steps ahead in registers so its L3-latency loads
// never sit on the critical path.

__device__ void gru_scan(const float* __restrict__ GI,   // [NB][192] = wih@x + bih
                         const float* __restrict__ whh,  // [192][64]
                         const float* __restrict__ bhh,  // [192]
                         const float* __restrict__ h0,   // [64] or nullptr (zeros)
                         float* __restrict__ ys,         // [NB][64] out
                         float* __restrict__ hfin_out)   // [64] out or nullptr
{
    __shared__ float part[2][3][4][DIM];
    const int tid  = threadIdx.x;
    const int lane = tid & 63;
    const int wave = tid >> 6;
    const int k0   = wave * 16;

    // preload whh slice: rows {lane, 64+lane, 128+lane}, cols [k0, k0+16)
    float wr[16], wz[16], wn[16];
#pragma unroll
    for (int i = 0; i < 16; ++i) {
        wr[i] = whh[(0 * DIM + lane) * DIM + k0 + i];
        wz[i] = whh[(1 * DIM + lane) * DIM + k0 + i];
        wn[i] = whh[(2 * DIM + lane) * DIM + k0 + i];
    }
    const float br = bhh[lane], bz = bhh[DIM + lane], bn = bhh[2 * DIM + lane];

    float h = h0 ? h0[lane] : 0.0f;

    // GI register pipeline: gA = step t (even), gB = step t+1 (odd)
    float gA0 = GI[0 * G3 + lane], gA1 = GI[0 * G3 + DIM + lane], gA2 = GI[0 * G3 + 2 * DIM + lane];
    float gB0 = GI[1 * G3 + lane], gB1 = GI[1 * G3 + DIM + lane], gB2 = GI[1 * G3 + 2 * DIM + lane];

    for (int t = 0; t < NB; t += 2) {
        // ---- even step (slot 0, gates from gA) ----
        {
            const int tp = (t + 2 < NB) ? t + 2 : NB - 1;
            const float* gp = GI + tp * G3;
            float pA0 = gp[lane], pA1 = gp[DIM + lane], pA2 = gp[2 * DIM + lane];

            float pr0 = 0.f, pr1 = 0.f, pz0 = 0.f, pz1 = 0.f, pn0 = 0.f, pn1 = 0.f;
#pragma unroll
            for (int i = 0; i < 8; ++i) {
                float hk = bcast(h, k0 + i);
                pr0 = fmaf(wr[i], hk, pr0); pz0 = fmaf(wz[i], hk, pz0); pn0 = fmaf(wn[i], hk, pn0);
            }
#pragma unroll
            for (int i = 8; i < 16; ++i) {
                float hk = bcast(h, k0 + i);
                pr1 = fmaf(wr[i], hk, pr1); pz1 = fmaf(wz[i], hk, pz1); pn1 = fmaf(wn[i], hk, pn1);
            }
            part[0][0][wave][lane] = pr0 + pr1;
            part[0][1][wave][lane] = pz0 + pz1;
            part[0][2][wave][lane] = pn0 + pn1;
            barrier_lds();

            float ghr = br + part[0][0][0][lane] + part[0][0][1][lane] + part[0][0][2][lane] + part[0][0][3][lane];
            float ghz = bz + part[0][1][0][lane] + part[0][1][1][lane] + part[0][1][2][lane] + part[0][1][3][lane];
            float ghn = bn + part[0][2][0][lane] + part[0][2][1][lane] + part[0][2][2][lane] + part[0][2][3][lane];
            float r = sigmoidf_(gA0 + ghr);
            float z = sigmoidf_(gA1 + ghz);
            float n = tanhf_(gA2 + r * ghn);
            h = n + z * (h - n);
            if (wave == 0) ys[t * DIM + lane] = h;
            gA0 = pA0; gA1 = pA1; gA2 = pA2;
        }
        // ---- odd step (slot 1, gates from gB) ----
        {
            const int tp = (t + 3 < NB) ? t + 3 : NB - 1;
            const float* gp = GI + tp * G3;
            float pB0 = gp[lane], pB1 = gp[DIM + lane], pB2 = gp[2 * DIM + lane];

            float pr0 = 0.f, pr1 = 0.f, pz0 = 0.f, pz1 = 0.f, pn0 = 0.f, pn1 = 0.f;
#pragma unroll
            for (int i = 0; i < 8; ++i) {
                float hk = bcast(h, k0 + i);
                pr0 = fmaf(wr[i], hk, pr0); pz0 = fmaf(wz[i], hk, pz0); pn0 = fmaf(wn[i], hk, pn0);
            }
#pragma unroll
            for (int i = 8; i < 16; ++i) {
                float hk = bcast(h, k0 + i);
                pr1 = fmaf(wr[i], hk, pr1); pz1 = fmaf(wz[i], hk, pz1); pn1 = fmaf(wn[i], hk, pn1);
            }
            part[1][0][wave][lane] = pr0 + pr1;
            part[1][1][wave][lane] = pz0 + pz1;
            part[1][2][wave][lane] = pn0 + pn1;
            barrier_lds();

            float ghr = br + part[1][0][0][lane] + part[1][0][1][lane] + part[1][0][2][lane] + part[1][0][3][lane];
            float ghz = bz + part[1][1][0][lane] + part[1][1][1][lane] + part[1][1][2][lane] + part[1][1][3][lane];
            float ghn = bn + part[1][2][0][lane] + part[1][2][1][lane] + part[1][2][2][lane] + part[1][2][3][lane];
            float r = sigmoidf_(gB0 + ghr);
            float z = sigmoidf_(gB1 + ghz);
            float n = tanhf_(gB2 + r * ghn);
            h = n + z * (h - n);
            if (wave == 0) ys[(t + 1) * DIM + lane] = h;
            gB0 = pB0; gB1 = pB1; gB2 = pB2;
        }
    }
    if (wave == 0 && hfin_out) hfin_out[lane] = h;
}

// ---------- K0 / K2: GI = wih @ x + bih (+ per-relation sqnorm on extra blocks) ----------

__global__ __launch_bounds__(64) void gi_kernel(const float* __restrict__ xsrc,
                                                const int* __restrict__ idx,    // nullptr => direct
                                                const float* __restrict__ wih,  // [192][64]
                                                const float* __restrict__ bih,  // [192]
                                                const float* __restrict__ Rel,  // [32][4096]
                                                float* __restrict__ GI,         // [NB][192]
                                                float* __restrict__ relnorm)    // [32]
{
    const int blk = blockIdx.x, lane = threadIdx.x;
    if (blk >= NB) {
        // per-relation squared norm
        const int r = blk - NB;
        const float* R = Rel + r * DIM * DIM;
        float a = 0.0f;
#pragma unroll 4
        for (int i = 0; i < DIM; ++i) { float v = R[i * DIM + lane]; a = fmaf(v, v, a); }
        a = wave_sum(a);
        if (lane == 0) relnorm[r] = a;
        return;
    }
    const int b = blk;
    float xv = idx ? xsrc[idx[b] * DIM + lane] : xsrc[b * DIM + lane];
    float a0 = bih[lane], a1 = bih[DIM + lane], a2 = bih[2 * DIM + lane];
    const float* w0 = wih + (0 * DIM + lane) * DIM;
    const float* w1 = wih + (1 * DIM + lane) * DIM;
    const float* w2 = wih + (2 * DIM + lane) * DIM;
#pragma unroll 4
    for (int k = 0; k < DIM; ++k) {
        float xk = bcast(xv, k);
        a0 = fmaf(w0[k], xk, a0);
        a1 = fmaf(w1[k], xk, a1);
        a2 = fmaf(w2[k], xk, a2);
    }
    float* gp = GI + b * G3;
    gp[lane] = a0; gp[DIM + lane] = a1; gp[2 * DIM + lane] = a2;
}

// ---------- K1: block 0 = GRU hop0; blocks 1..512 = attention hop0 + KGE(both hops) + L2 ----------

__global__ __launch_bounds__(256) void fused0(const float* __restrict__ E,
                                              const float* __restrict__ Rel,
                                              const int* __restrict__ items,
                                              const int* __restrict__ mh,
                                              const int* __restrict__ mr,
                                              const int* __restrict__ mt,
                                              const float* __restrict__ GI,
                                              const float* __restrict__ whh,
                                              const float* __restrict__ bhh,
                                              const float* __restrict__ relnorm,
                                              float* __restrict__ ys0,
                                              float* __restrict__ hfin,
                                              float* __restrict__ o0,
                                              float* __restrict__ kge_part,   // [NB][2]
                                              float* __restrict__ l2_part)    // [NB]
{
    if (blockIdx.x == 0) { gru_scan(GI, whh, bhh, nullptr, ys0, hfin); return; }

    const int b = blockIdx.x - 1;
    const int tid = threadIdx.x, lane = tid & 63, wave = tid >> 6;
    __shared__ float logits[NM], probs[NM], opart[4][DIM], wred[4][4];

    float iv = E[items[b] * DIM + lane];
    float kge0 = 0.0f, kge1 = 0.0f, l2acc = 0.0f, r2acc = 0.0f;

    // hop 0: attention logits + KGE + L2
    for (int mm = 0; mm < 8; ++mm) {
        const int m = wave * 8 + mm;
        const int base = b * NM + m;                 // hop 0
        const int hidx = mh[base], ridx = mr[base], tidx = mt[base];
        float hv = E[hidx * DIM + lane];
        float tv = E[tidx * DIM + lane];
        l2acc = fmaf(hv, hv, l2acc);
        l2acc = fmaf(tv, tv, l2acc);
        r2acc += relnorm[ridx];
        const float* R = Rel + ridx * DIM * DIM;
        float accA = 0.0f, accK = 0.0f;
#pragma unroll 4
        for (int i = 0; i < DIM; ++i) {
            float rv = R[i * DIM + lane];            // coalesced row read
            accA = fmaf(bcast(iv, i), rv, accA);     // col-sums of item^T R
            accK = fmaf(bcast(hv, i), rv, accK);     // col-sums of h^T R
        }
        float la = wave_sum(accA * hv);              // item^T R h
        float lk = wave_sum(accK * tv);              // h^T R t
        if (lane == 0) logits[m] = la;
        kge0 += sigmoidf_(lk);
    }
    // hop 1: KGE + L2 only (independent of GRU)
    for (int mm = 0; mm < 8; ++mm) {
        const int m = wave * 8 + mm;
        const int base = NB * NM + b * NM + m;       // hop 1
        const int hidx = mh[base], ridx = mr[base], tidx = mt[base];
        float hv = E[hidx * DIM + lane];
        float tv = E[tidx * DIM + lane];
        l2acc = fmaf(hv, hv, l2acc);
        l2acc = fmaf(tv, tv, l2acc);
        r2acc += relnorm[ridx];
        const float* R = Rel + ridx * DIM * DIM;
        float accK = 0.0f;
#pragma unroll 4
        for (int i = 0; i < DIM; ++i)
            accK = fmaf(bcast(hv, i), R[i * DIM + lane], accK);
        kge1 += sigmoidf_(wave_sum(accK * tv));
    }
    __syncthreads();

    // softmax over 32 memories (wave 0)
    if (wave == 0) {
        float v = (lane < NM) ? logits[lane] : -1e30f;
        float mx = wave_max(v);
        float e = (lane < NM) ? __expf(v - mx) : 0.0f;
        float ssum = wave_sum(e);
        if (lane < NM) probs[lane] = e / ssum;
    }
    __syncthreads();

    // o = sum_m p_m * t_emb
    float od = 0.0f;
    for (int mm = 0; mm < 8; ++mm) {
        const int m = wave * 8 + mm;
        const int tidx = mt[b * NM + m];
        od = fmaf(probs[m], E[tidx * DIM + lane], od);
    }
    opart[wave][lane] = od;
    float l2tot = wave_sum(l2acc);
    if (lane == 0) { wred[wave][0] = kge0; wred[wave][1] = kge1; wred[wave][2] = l2tot + r2acc; }
    __syncthreads();
    if (wave == 0)
        o0[b * DIM + lane] = opart[0][lane] + opart[1][lane] + opart[2][lane] + opart[3][lane];
    if (tid == 0) {
        kge_part[b * 2 + 0] = wred[0][0] + wred[1][0] + wred[2][0] + wred[3][0];
        kge_part[b * 2 + 1] = wred[0][1] + wred[1][1] + wred[2][1] + wred[3][1];
        l2_part[b]          = wred[0][2] + wred[1][2] + wred[2][2] + wred[3][2];
    }
}

// ---------- K3: block 0 = GRU hop1; blocks 1..512 = attention hop1 + o_sum ----------

__global__ __launch_bounds__(256) void fused1(const float* __restrict__ E,
                                              const float* __restrict__ Rel,
                                              const int* __restrict__ mh,
                                              const int* __restrict__ mr,
                                              const int* __restrict__ mt,
                                              const float* __restrict__ GI,
                                              const float* __restrict__ whh,
                                              const float* __restrict__ bhh,
                                              const float* __restrict__ hfin,
                                              const float* __restrict__ ys0,
                                              float* __restrict__ ys1,
                                              const float* __restrict__ o0,
                                              float* __restrict__ osum)
{
    if (blockIdx.x == 0) { gru_scan(GI, whh, bhh, hfin, ys1, nullptr); return; }

    const int b = blockIdx.x - 1;
    const int tid = threadIdx.x, lane = tid & 63, wave = tid >> 6;
    __shared__ float logits[NM], probs[NM], opart[4][DIM];

    float iv = ys0[b * DIM + lane];   // item_emb after 1 GRU pass

    for (int mm = 0; mm < 8; ++mm) {
        const int m = wave * 8 + mm;
        const int base = NB * NM + b * NM + m;       // hop 1
        const int hidx = mh[base], ridx = mr[base];
        float hv = E[hidx * DIM + lane];
        const float* R = Rel + ridx * DIM * DIM;
        float accA = 0.0f;
#pragma unroll 4
        for (int i = 0; i < DIM; ++i)
            accA = fmaf(bcast(iv, i), R[i * DIM + lane], accA);
        float la = wave_sum(accA * hv);
        if (lane == 0) logits[m] = la;
    }
    __syncthreads();
    if (wave == 0) {
        float v = (lane < NM) ? logits[lane] : -1e30f;
        float mx = wave_max(v);
        float e = (lane < NM) ? __expf(v - mx) : 0.0f;
        float ssum = wave_sum(e);
        if (lane < NM) probs[lane] = e / ssum;
    }
    __syncthreads();
    float od = 0.0f;
    for (int mm = 0; mm < 8; ++mm) {
        const int m = wave * 8 + mm;
        const int tidx = mt[NB * NM + b * NM + m];
        od = fmaf(probs[m], E[tidx * DIM + lane], od);
    }
    opart[wave][lane] = od;
    __syncthreads();
    if (wave == 0)
        osum[b * DIM + lane] = o0[b * DIM + lane] +
            opart[0][lane] + opart[1][lane] + opart[2][lane] + opart[3][lane];
}

// ---------- K4: scores + losses ----------

__global__ __launch_bounds__(512) void finalize(const float* __restrict__ ys1,
                                                const float* __restrict__ osum,
                                                const int* __restrict__ labels,
                                                const float* __restrict__ kge_part,
                                                const float* __restrict__ l2_part,
                                                float* __restrict__ out)
{
    __shared__ float red[512];
    const int tid = threadIdx.x;

    float dot = 0.0f;
    const float* a = ys1 + tid * DIM;
    const float* c = osum + tid * DIM;
#pragma unroll 8
    for (int k = 0; k < DIM; ++k) dot = fmaf(a[k], c[k], dot);
    float score = sigmoidf_(dot);
    out[tid] = score;

    float s = fminf(fmaxf(score, EPSC), 1.0f - EPSC);
    float term = labels[tid] ? logf(s) : log1pf(-s);

    // three deterministic block reductions
    float bsum, ksum, lsum;
    {
        red[tid] = term; __syncthreads();
#pragma unroll
        for (int st = 256; st > 0; st >>= 1) { if (tid < st) red[tid] += red[tid + st]; __syncthreads(); }
        bsum = red[0]; __syncthreads();
    }
    {
        red[tid] = kge_part[2 * tid] + kge_part[2 * tid + 1]; __syncthreads();
#pragma unroll
        for (int st = 256; st > 0; st >>= 1) { if (tid < st) red[tid] += red[tid + st]; __syncthreads(); }
        ksum = red[0]; __syncthreads();
    }
    {
        red[tid] = l2_part[tid]; __syncthreads();
#pragma unroll
        for (int st = 256; st > 0; st >>= 1) { if (tid < st) red[tid] += red[tid + st]; __syncthreads(); }
        lsum = red[0];
    }

    if (tid == 0) {
        float base = -bsum / (float)NB;
        float kge  = -KGE_W * ksum / (float)(NB * NM);
        float l2   = L2_W * lsum;
        out[NB + 0] = base;
        out[NB + 1] = kge;
        out[NB + 2] = l2;
        out[NB + 3] = base + kge + l2;
    }
}

// ---------- host ----------

extern "C" void kernel_launch(void* const* d_in, const int* in_sizes, int n_in,
                              void* d_out, int out_size, void* d_ws, size_t ws_size,
                              hipStream_t stream) {
    const int*   items  = (const int*)d_in[0];
    const int*   labels = (const int*)d_in[1];
    const int*   mh     = (const int*)d_in[2];
    const int*   mr     = (const int*)d_in[3];
    const int*   mt     = (const int*)d_in[4];
    const float* E      = (const float*)d_in[5];
    const float* Rel    = (const float*)d_in[6];
    const float* wih    = (const float*)d_in[7];
    const float* whh    = (const float*)d_in[8];
    const float* bih    = (const float*)d_in[9];
    const float* bhh    = (const float*)d_in[10];
    float* out = (float*)d_out;
    float* ws  = (float*)d_ws;

    // workspace layout (floats)
    float* GI      = ws;                 // 512*192 = 98304
    float* ys0     = GI + 98304;         // 32768
    float* ys1     = ys0 + 32768;        // 32768
    float* hfin    = ys1 + 32768;        // 64
    float* o0      = hfin + 64;          // 32768
    float* osum    = o0 + 32768;         // 32768
    float* relnorm = osum + 32768;       // 32
    float* kge_p   = relnorm + 32;       // 1024
    float* l2_p    = kge_p + 1024;       // 512

    // K0: GI for hop 0 (x = entity_emb[items]) + per-relation sqnorms
    gi_kernel<<<NB + NRELS, 64, 0, stream>>>(E, items, wih, bih, Rel, GI, relnorm);
    // K1: GRU hop0 (block 0) || attention hop0 + KGE both hops + L2 partials
    fused0<<<NB + 1, 256, 0, stream>>>(E, Rel, items, mh, mr, mt, GI, whh, bhh,
                                       relnorm, ys0, hfin, o0, kge_p, l2_p);
    // K2: GI for hop 1 (x = ys0)
    gi_kernel<<<NB, 64, 0, stream>>>(ys0, nullptr, wih, bih, Rel, GI, relnorm);
    // K3: GRU hop1 (block 0) || attention hop1 + o_sum
    fused1<<<NB + 1, 256, 0, stream>>>(E, Rel, mh, mr, mt, GI, whh, bhh, hfin,
                                       ys0, ys1, o0, osum);
    // K4: scores + losses
    finalize<<<1, 512, 0, stream>>>(ys1, osum, labels, kge_p, l2_p, out);
}

// Round 3
// 541.048 us; speedup vs baseline: 1.2959x; 1.2959x over previous
//
#include <hip/hip_runtime.h>

#define DIM   64
#define G3    192      // 3*DIM
#define NB    512      // BATCH
#define NM    32       // N_MEM
#define NRELS 32
#define KGE_W 0.01f
#define L2_W  1e-7f
#define EPSC  1e-7f

// ---------- helpers ----------

__device__ inline float bcast(float v, int srclane) {
    // wave-uniform lane broadcast (index is compile-time constant at all call sites)
    return __int_as_float(__builtin_amdgcn_readlane(__float_as_int(v), srclane));
}

__device__ inline float sigmoidf_(float x) { return 1.0f / (1.0f + __expf(-x)); }
__device__ inline float tanhf_(float x)    { return 1.0f - 2.0f / (1.0f + __expf(2.0f * x)); }

__device__ inline float wave_sum(float v) {
#pragma unroll
    for (int off = 32; off > 0; off >>= 1) v += __shfl_xor(v, off, 64);
    return v;
}
__device__ inline float wave_max(float v) {
#pragma unroll
    for (int off = 32; off > 0; off >>= 1) v = fmaxf(v, __shfl_xor(v, off, 64));
    return v;
}

// ---------- GRU scan: ONE wave, whole whh in VGPRs, no LDS, no barriers ----------
// Lane i owns output rows {i, 64+i, 128+i} of the 192x64 matvec. State h is
// distributed (lane k holds h_k); broadcast via v_readlane. All gate math and
// the h-update are lane-local. Critical path per step is pure VALU issue:
// 64 readlane + 192 FMA (12 split accumulator chains) + 2 sigmoid + tanh.

__device__ void gru_scan(const float* __restrict__ GI,   // [NB][192] = wih@x + bih
                         const float* __restrict__ whh,  // [192][64]
                         const float* __restrict__ bhh,  // [192]
                         const float* __restrict__ h0,   // [64] or nullptr (zeros)
                         float* __restrict__ ys,         // [NB][64] out
                         float* __restrict__ hfin_out)   // [64] out or nullptr
{
    const int lane = threadIdx.x & 63;

    // whh rows {lane, 64+lane, 128+lane} -> 192 VGPRs
    float wr[DIM], wz[DIM], wn[DIM];
    {
        const float4* r4 = (const float4*)(whh + (0 * DIM + lane) * DIM);
        const float4* z4 = (const float4*)(whh + (1 * DIM + lane) * DIM);
        const float4* n4 = (const float4*)(whh + (2 * DIM + lane) * DIM);
#pragma unroll
        for (int i = 0; i < 16; ++i) {
            float4 a = r4[i]; wr[4*i] = a.x; wr[4*i+1] = a.y; wr[4*i+2] = a.z; wr[4*i+3] = a.w;
            float4 b = z4[i]; wz[4*i] = b.x; wz[4*i+1] = b.y; wz[4*i+2] = b.z; wz[4*i+3] = b.w;
            float4 c = n4[i]; wn[4*i] = c.x; wn[4*i+1] = c.y; wn[4*i+2] = c.z; wn[4*i+3] = c.w;
        }
    }
    const float br = bhh[lane], bz = bhh[DIM + lane], bn = bhh[2 * DIM + lane];

    float h = h0 ? h0[lane] : 0.0f;

    // GI register pipeline, distance 1
    float c0 = GI[lane], c1 = GI[DIM + lane], c2 = GI[2 * DIM + lane];

    for (int t = 0; t < NB; ++t) {
        const int tn = (t + 1 < NB) ? t + 1 : NB - 1;
        const float* gp = GI + tn * G3;
        float p0 = gp[lane], p1 = gp[DIM + lane], p2 = gp[2 * DIM + lane];

        float ar0 = 0.f, ar1 = 0.f, ar2 = 0.f, ar3 = 0.f;
        float az0 = 0.f, az1 = 0.f, az2 = 0.f, az3 = 0.f;
        float an0 = 0.f, an1 = 0.f, an2 = 0.f, an3 = 0.f;
#pragma unroll
        for (int k = 0; k < 16; ++k) {
            float hk = bcast(h, k);
            ar0 = fmaf(wr[k], hk, ar0); az0 = fmaf(wz[k], hk, az0); an0 = fmaf(wn[k], hk, an0);
        }
#pragma unroll
        for (int k = 16; k < 32; ++k) {
            float hk = bcast(h, k);
            ar1 = fmaf(wr[k], hk, ar1); az1 = fmaf(wz[k], hk, az1); an1 = fmaf(wn[k], hk, an1);
        }
#pragma unroll
        for (int k = 32; k < 48; ++k) {
            float hk = bcast(h, k);
            ar2 = fmaf(wr[k], hk, ar2); az2 = fmaf(wz[k], hk, az2); an2 = fmaf(wn[k], hk, an2);
        }
#pragma unroll
        for (int k = 48; k < 64; ++k) {
            float hk = bcast(h, k);
            ar3 = fmaf(wr[k], hk, ar3); az3 = fmaf(wz[k], hk, az3); an3 = fmaf(wn[k], hk, an3);
        }
        float ghr = ((ar0 + ar1) + (ar2 + ar3)) + br;
        float ghz = ((az0 + az1) + (az2 + az3)) + bz;
        float ghn = ((an0 + an1) + (an2 + an3)) + bn;

        float r = sigmoidf_(c0 + ghr);
        float z = sigmoidf_(c1 + ghz);
        float n = tanhf_(c2 + r * ghn);
        h = n + z * (h - n);               // (1-z)*n + z*h

        ys[t * DIM + lane] = h;
        c0 = p0; c1 = p1; c2 = p2;
    }
    if (hfin_out) hfin_out[lane] = h;
}

// ---------- K0 / K2: GI = wih @ x + bih (+ per-relation sqnorm on extra blocks) ----------

__global__ __launch_bounds__(64) void gi_kernel(const float* __restrict__ xsrc,
                                                const int* __restrict__ idx,    // nullptr => direct
                                                const float* __restrict__ wih,  // [192][64]
                                                const float* __restrict__ bih,  // [192]
                                                const float* __restrict__ Rel,  // [32][4096]
                                                float* __restrict__ GI,         // [NB][192]
                                                float* __restrict__ relnorm)    // [32]
{
    const int blk = blockIdx.x, lane = threadIdx.x;
    if (blk >= NB) {
        // per-relation squared norm
        const int r = blk - NB;
        const float* R = Rel + r * DIM * DIM;
        float a = 0.0f;
#pragma unroll 4
        for (int i = 0; i < DIM; ++i) { float v = R[i * DIM + lane]; a = fmaf(v, v, a); }
        a = wave_sum(a);
        if (lane == 0) relnorm[r] = a;
        return;
    }
    const int b = blk;
    float xv = idx ? xsrc[idx[b] * DIM + lane] : xsrc[b * DIM + lane];
    float a0 = bih[lane], a1 = bih[DIM + lane], a2 = bih[2 * DIM + lane];
    const float* w0 = wih + (0 * DIM + lane) * DIM;
    const float* w1 = wih + (1 * DIM + lane) * DIM;
    const float* w2 = wih + (2 * DIM + lane) * DIM;
#pragma unroll 4
    for (int k = 0; k < DIM; ++k) {
        float xk = bcast(xv, k);
        a0 = fmaf(w0[k], xk, a0);
        a1 = fmaf(w1[k], xk, a1);
        a2 = fmaf(w2[k], xk, a2);
    }
    float* gp = GI + b * G3;
    gp[lane] = a0; gp[DIM + lane] = a1; gp[2 * DIM + lane] = a2;
}

// ---------- K1: block 0 = GRU hop0; blocks 1..512 = attention hop0 + KGE(both hops) + L2 ----------

__global__ __launch_bounds__(256, 1) void fused0(const float* __restrict__ E,
                                              const float* __restrict__ Rel,
                                              const int* __restrict__ items,
                                              const int* __restrict__ mh,
                                              const int* __restrict__ mr,
                                              const int* __restrict__ mt,
                                              const float* __restrict__ GI,
                                              const float* __restrict__ whh,
                                              const float* __restrict__ bhh,
                                              const float* __restrict__ relnorm,
                                              float* __restrict__ ys0,
                                              float* __restrict__ hfin,
                                              float* __restrict__ o0,
                                              float* __restrict__ kge_part,   // [NB][2]
                                              float* __restrict__ l2_part)    // [NB]
{
    if (blockIdx.x == 0) {
        if (threadIdx.x < 64) gru_scan(GI, whh, bhh, nullptr, ys0, hfin);
        return;
    }

    const int b = blockIdx.x - 1;
    const int tid = threadIdx.x, lane = tid & 63, wave = tid >> 6;
    __shared__ float logits[NM], probs[NM], opart[4][DIM], wred[4][4];

    float iv = E[items[b] * DIM + lane];
    float kge0 = 0.0f, kge1 = 0.0f, l2acc = 0.0f, r2acc = 0.0f;

    // hop 0: attention logits + KGE + L2
    for (int mm = 0; mm < 8; ++mm) {
        const int m = wave * 8 + mm;
        const int base = b * NM + m;                 // hop 0
        const int hidx = mh[base], ridx = mr[base], tidx = mt[base];
        float hv = E[hidx * DIM + lane];
        float tv = E[tidx * DIM + lane];
        l2acc = fmaf(hv, hv, l2acc);
        l2acc = fmaf(tv, tv, l2acc);
        r2acc += relnorm[ridx];
        const float* R = Rel + ridx * DIM * DIM;
        float accA = 0.0f, accK = 0.0f;
#pragma unroll 4
        for (int i = 0; i < DIM; ++i) {
            float rv = R[i * DIM + lane];            // coalesced row read
            accA = fmaf(bcast(iv, i), rv, accA);     // col-sums of item^T R
            accK = fmaf(bcast(hv, i), rv, accK);     // col-sums of h^T R
        }
        float la = wave_sum(accA * hv);              // item^T R h
        float lk = wave_sum(accK * tv);              // h^T R t
        if (lane == 0) logits[m] = la;
        kge0 += sigmoidf_(lk);
    }
    // hop 1: KGE + L2 only (independent of GRU)
    for (int mm = 0; mm < 8; ++mm) {
        const int m = wave * 8 + mm;
        const int base = NB * NM + b * NM + m;       // hop 1
        const int hidx = mh[base], ridx = mr[base], tidx = mt[base];
        float hv = E[hidx * DIM + lane];
        float tv = E[tidx * DIM + lane];
        l2acc = fmaf(hv, hv, l2acc);
        l2acc = fmaf(tv, tv, l2acc);
        r2acc += relnorm[ridx];
        const float* R = Rel + ridx * DIM * DIM;
        float accK = 0.0f;
#pragma unroll 4
        for (int i = 0; i < DIM; ++i)
            accK = fmaf(bcast(hv, i), R[i * DIM + lane], accK);
        kge1 += sigmoidf_(wave_sum(accK * tv));
    }
    __syncthreads();

    // softmax over 32 memories (wave 0)
    if (wave == 0) {
        float v = (lane < NM) ? logits[lane] : -1e30f;
        float mx = wave_max(v);
        float e = (lane < NM) ? __expf(v - mx) : 0.0f;
        float ssum = wave_sum(e);
        if (lane < NM) probs[lane] = e / ssum;
    }
    __syncthreads();

    // o = sum_m p_m * t_emb
    float od = 0.0f;
    for (int mm = 0; mm < 8; ++mm) {
        const int m = wave * 8 + mm;
        const int tidx = mt[b * NM + m];
        od = fmaf(probs[m], E[tidx * DIM + lane], od);
    }
    opart[wave][lane] = od;
    float l2tot = wave_sum(l2acc);
    if (lane == 0) { wred[wave][0] = kge0; wred[wave][1] = kge1; wred[wave][2] = l2tot + r2acc; }
    __syncthreads();
    if (wave == 0)
        o0[b * DIM + lane] = opart[0][lane] + opart[1][lane] + opart[2][lane] + opart[3][lane];
    if (tid == 0) {
        kge_part[b * 2 + 0] = wred[0][0] + wred[1][0] + wred[2][0] + wred[3][0];
        kge_part[b * 2 + 1] = wred[0][1] + wred[1][1] + wred[2][1] + wred[3][1];
        l2_part[b]          = wred[0][2] + wred[1][2] + wred[2][2] + wred[3][2];
    }
}

// ---------- K3: block 0 = GRU hop1; blocks 1..512 = attention hop1 + o_sum ----------

__global__ __launch_bounds__(256, 1) void fused1(const float* __restrict__ E,
                                              const float* __restrict__ Rel,
                                              const int* __restrict__ mh,
                                              const int* __restrict__ mr,
                                              const int* __restrict__ mt,
                                              const float* __restrict__ GI,
                                              const float* __restrict__ whh,
                                              const float* __restrict__ bhh,
                                              const float* __restrict__ hfin,
                                              const float* __restrict__ ys0,
                                              float* __restrict__ ys1,
                                              const float* __restrict__ o0,
                                              float* __restrict__ osum)
{
    if (blockIdx.x == 0) {
        if (threadIdx.x < 64) gru_scan(GI, whh, bhh, hfin, ys1, nullptr);
        return;
    }

    const int b = blockIdx.x - 1;
    const int tid = threadIdx.x, lane = tid & 63, wave = tid >> 6;
    __shared__ float logits[NM], probs[NM], opart[4][DIM];

    float iv = ys0[b * DIM + lane];   // item_emb after 1 GRU pass

    for (int mm = 0; mm < 8; ++mm) {
        const int m = wave * 8 + mm;
        const int base = NB * NM + b * NM + m;       // hop 1
        const int hidx = mh[base], ridx = mr[base];
        float hv = E[hidx * DIM + lane];
        const float* R = Rel + ridx * DIM * DIM;
        float accA = 0.0f;
#pragma unroll 4
        for (int i = 0; i < DIM; ++i)
            accA = fmaf(bcast(iv, i), R[i * DIM + lane], accA);
        float la = wave_sum(accA * hv);
        if (lane == 0) logits[m] = la;
    }
    __syncthreads();
    if (wave == 0) {
        float v = (lane < NM) ? logits[lane] : -1e30f;
        float mx = wave_max(v);
        float e = (lane < NM) ? __expf(v - mx) : 0.0f;
        float ssum = wave_sum(e);
        if (lane < NM) probs[lane] = e / ssum;
    }
    __syncthreads();
    float od = 0.0f;
    for (int mm = 0; mm < 8; ++mm) {
        const int m = wave * 8 + mm;
        const int tidx = mt[NB * NM + b * NM + m];
        od = fmaf(probs[m], E[tidx * DIM + lane], od);
    }
    opart[wave][lane] = od;
    __syncthreads();
    if (wave == 0)
        osum[b * DIM + lane] = o0[b * DIM + lane] +
            opart[0][lane] + opart[1][lane] + opart[2][lane] + opart[3][lane];
}

// ---------- K4: scores + losses ----------

__global__ __launch_bounds__(512) void finalize(const float* __restrict__ ys1,
                                                const float* __restrict__ osum,
                                                const int* __restrict__ labels,
                                                const float* __restrict__ kge_part,
                                                const float* __restrict__ l2_part,
                                                float* __restrict__ out)
{
    __shared__ float red[512];
    const int tid = threadIdx.x;

    float dot = 0.0f;
    const float* a = ys1 + tid * DIM;
    const float* c = osum + tid * DIM;
#pragma unroll 8
    for (int k = 0; k < DIM; ++k) dot = fmaf(a[k], c[k], dot);
    float score = sigmoidf_(dot);
    out[tid] = score;

    float s = fminf(fmaxf(score, EPSC), 1.0f - EPSC);
    float term = labels[tid] ? logf(s) : log1pf(-s);

    // three deterministic block reductions
    float bsum, ksum, lsum;
    {
        red[tid] = term; __syncthreads();
#pragma unroll
        for (int st = 256; st > 0; st >>= 1) { if (tid < st) red[tid] += red[tid + st]; __syncthreads(); }
        bsum = red[0]; __syncthreads();
    }
    {
        red[tid] = kge_part[2 * tid] + kge_part[2 * tid + 1]; __syncthreads();
#pragma unroll
        for (int st = 256; st > 0; st >>= 1) { if (tid < st) red[tid] += red[tid + st]; __syncthreads(); }
        ksum = red[0]; __syncthreads();
    }
    {
        red[tid] = l2_part[tid]; __syncthreads();
#pragma unroll
        for (int st = 256; st > 0; st >>= 1) { if (tid < st) red[tid] += red[tid + st]; __syncthreads(); }
        lsum = red[0];
    }

    if (tid == 0) {
        float base = -bsum / (float)NB;
        float kge  = -KGE_W * ksum / (float)(NB * NM);
        float l2   = L2_W * lsum;
        out[NB + 0] = base;
        out[NB + 1] = kge;
        out[NB + 2] = l2;
        out[NB + 3] = base + kge + l2;
    }
}

// ---------- host ----------

extern "C" void kernel_launch(void* const* d_in, const int* in_sizes, int n_in,
                              void* d_out, int out_size, void* d_ws, size_t ws_size,
                              hipStream_t stream) {
    const int*   items  = (const int*)d_in[0];
    const int*   labels = (const int*)d_in[1];
    const int*   mh     = (const int*)d_in[2];
    const int*   mr     = (const int*)d_in[3];
    const int*   mt     = (const int*)d_in[4];
    const float* E      = (const float*)d_in[5];
    const float* Rel    = (const float*)d_in[6];
    const float* wih    = (const float*)d_in[7];
    const float* whh    = (const float*)d_in[8];
    const float* bih    = (const float*)d_in[9];
    const float* bhh    = (const float*)d_in[10];
    float* out = (float*)d_out;
    float* ws  = (float*)d_ws;

    // workspace layout (floats)
    float* GI      = ws;                 // 512*192 = 98304
    float* ys0     = GI + 98304;         // 32768
    float* ys1     = ys0 + 32768;        // 32768
    float* hfin    = ys1 + 32768;        // 64
    float* o0      = hfin + 64;          // 32768
    float* osum    = o0 + 32768;         // 32768
    float* relnorm = osum + 32768;       // 32
    float* kge_p   = relnorm + 32;       // 1024
    float* l2_p    = kge_p + 1024;       // 512

    // K0: GI for hop 0 (x = entity_emb[items]) + per-relation sqnorms
    gi_kernel<<<NB + NRELS, 64, 0, stream>>>(E, items, wih, bih, Rel, GI, relnorm);
    // K1: GRU hop0 (block 0, single wave) || attention hop0 + KGE both hops + L2 partials
    fused0<<<NB + 1, 256, 0, stream>>>(E, Rel, items, mh, mr, mt, GI, whh, bhh,
                                       relnorm, ys0, hfin, o0, kge_p, l2_p);
    // K2: GI for hop 1 (x = ys0)
    gi_kernel<<<NB, 64, 0, stream>>>(ys0, nullptr, wih, bih, Rel, GI, relnorm);
    // K3: GRU hop1 (block 0, single wave) || attention hop1 + o_sum
    fused1<<<NB + 1, 256, 0, stream>>>(E, Rel, mh, mr, mt, GI, whh, bhh, hfin,
                                       ys0, ys1, o0, osum);
    // K4: scores + losses
    finalize<<<1, 512, 0, stream>>>(ys1, osum, labels, kge_p, l2_p, out);
}